// Round 1
// baseline (1006.755 us; speedup 1.0000x reference)
//
#include <hip/hip_runtime.h>
#include <cstdint>

// Problem constants (from reference)
#define GRID_W 96
#define GRID_L 96
#define GRID_H 48
#define NVOX (GRID_W * GRID_L * GRID_H)   // 442368
#define VOXEL_SIZE 0.05f
#define MIN_PTS 10
#define BATCH 4
#define CHANS 16
#define NPTS (480 * 640)                  // 307200 points per batch

// Monotone float <-> uint mapping so unsigned atomicMax == float max.
__device__ __forceinline__ unsigned flip_f32(float f) {
    unsigned u = __float_as_uint(f);
    unsigned mask = (unsigned)(-(int)(u >> 31)) | 0x80000000u;
    return u ^ mask;
}
__device__ __forceinline__ float unflip_f32(unsigned u) {
    unsigned mask = ((u >> 31) - 1u) | 0x80000000u;
    return __uint_as_float(u ^ mask);
}

// flip(-inf) = ~0xFF800000 = 0x007FFFFF : identity element for the uint max.
#define FLIP_NEG_INF 0x007FFFFFu

// Kernel 1: initialize d_out in place.
//   [0, B*C*NVOX)            : voxeldata accumulator <- flip(-inf)
//   [B*C*NVOX, B*(C+1)*NVOX) : counts <- 0
__global__ void pv_init(uint4* __restrict__ out) {
    const int DATA4 = BATCH * CHANS * NVOX / 4;        // 7,077,888
    const int TOT4  = BATCH * (CHANS + 1) * NVOX / 4;  // 7,520,256
    int i = blockIdx.x * blockDim.x + threadIdx.x;
    if (i < TOT4) {
        unsigned val = (i < DATA4) ? FLIP_NEG_INF : 0u;
        uint4 v; v.x = val; v.y = val; v.z = val; v.w = val;
        out[i] = v;
    }
}

// Kernel 2: one thread per point; scatter count + 16-channel max.
__global__ void pv_scatter(const float* __restrict__ coords,   // [B,3,NPTS]
                           const float* __restrict__ attrs,    // [B,C,NPTS]
                           const float* __restrict__ origin,   // [B,3]
                           unsigned*    __restrict__ data_u,   // [B,C,NVOX]
                           unsigned*    __restrict__ cnt)      // [B,NVOX]
{
    int id = blockIdx.x * blockDim.x + threadIdx.x;
    if (id >= BATCH * NPTS) return;
    int b = id / NPTS;
    int n = id - b * NPTS;

    const float* cb = coords + (size_t)b * 3 * NPTS;
    float x = cb[n];
    float y = cb[NPTS + n];
    float z = cb[2 * NPTS + n];
    float ox = origin[b * 3 + 0];
    float oy = origin[b * 3 + 1];
    float oz = origin[b * 3 + 2];

    // IEEE f32 division + floorf: must match numpy reference binning exactly.
    int ix = (int)floorf((x - ox) / VOXEL_SIZE);
    int iy = (int)floorf((y - oy) / VOXEL_SIZE);
    int iz = (int)floorf((z - oz) / VOXEL_SIZE);

    if ((unsigned)ix < GRID_W && (unsigned)iy < GRID_L && (unsigned)iz < GRID_H) {
        int flat = ix * (GRID_L * GRID_H) + iy * GRID_H + iz;
        atomicAdd(&cnt[b * NVOX + flat], 1u);
        const float* ab = attrs + (size_t)b * CHANS * NPTS + n;
        unsigned*    db = data_u + (size_t)b * CHANS * NVOX + flat;
        #pragma unroll
        for (int c = 0; c < CHANS; ++c) {
            unsigned u = flip_f32(ab[(size_t)c * NPTS]);
            atomicMax(&db[(size_t)c * NVOX], u);
        }
    }
}

// Kernel 3: finalize in place. One thread per (b, voxel).
__global__ void pv_finalize(unsigned* __restrict__ data_u,  // [B,C,NVOX]
                            unsigned* __restrict__ cnt_u)   // [B,NVOX]
{
    int id = blockIdx.x * blockDim.x + threadIdx.x;
    if (id >= BATCH * NVOX) return;
    int b = id / NVOX;
    int v = id - b * NVOX;

    unsigned cnt = cnt_u[id];
    bool occ = (cnt >= MIN_PTS);
    ((float*)cnt_u)[id] = occ ? 1.0f : 0.0f;

    unsigned* db = data_u + (size_t)b * CHANS * NVOX + v;
    #pragma unroll
    for (int c = 0; c < CHANS; ++c) {
        float f = unflip_f32(db[(size_t)c * NVOX]);
        float val = (occ && isfinite(f)) ? f : 0.0f;
        ((float*)db)[(size_t)c * NVOX] = val;
    }
}

extern "C" void kernel_launch(void* const* d_in, const int* in_sizes, int n_in,
                              void* d_out, int out_size, void* d_ws, size_t ws_size,
                              hipStream_t stream) {
    const float* coords = (const float*)d_in[0];  // [4,3,480,640]
    const float* attrs  = (const float*)d_in[1];  // [4,16,480,640]
    const float* origin = (const float*)d_in[2];  // [4,3]

    float* out = (float*)d_out;
    unsigned* data_u = (unsigned*)out;                              // [B,C,NVOX]
    unsigned* cnt    = (unsigned*)(out + (size_t)BATCH * CHANS * NVOX); // [B,NVOX]

    const int TOT4 = BATCH * (CHANS + 1) * NVOX / 4;
    pv_init<<<(TOT4 + 255) / 256, 256, 0, stream>>>((uint4*)d_out);

    const int NP = BATCH * NPTS;
    pv_scatter<<<(NP + 255) / 256, 256, 0, stream>>>(coords, attrs, origin, data_u, cnt);

    const int NV = BATCH * NVOX;
    pv_finalize<<<(NV + 255) / 256, 256, 0, stream>>>(data_u, cnt);
}

// Round 2
// 375.425 us; speedup vs baseline: 2.6816x; 2.6816x over previous
//
#include <hip/hip_runtime.h>
#include <cstdint>

// Problem constants (from reference)
#define GRID_W 96
#define GRID_L 96
#define GRID_H 48
#define NVOX (GRID_W * GRID_L * GRID_H)   // 442368
#define VOXEL_SIZE 0.05f
#define MIN_PTS 10
#define BATCH 4
#define CHANS 16
#define NPTS (480 * 640)                  // 307200 points per batch
#define TOTPTS (BATCH * NPTS)             // 1228800
#define TOTVOX (BATCH * NVOX)             // 1769472

// Scan geometry: 864 blocks x 256 threads x 8 elems = 1769472 exactly.
#define SCAN_BLKS 864
#define SCAN_TPB 256
#define SCAN_EPT 8

// ---- workspace layout (bytes) ----
#define WS_OFF_OFFSETS 0
#define WS_OFF_VIDX    (TOTVOX * 4)                       // 7,077,888
#define WS_OFF_SUMS    (WS_OFF_VIDX + TOTPTS * 4)         // 11,993,088
#define WS_OFF_ROWS    (WS_OFF_SUMS + 4096)               // 11,997,184
#define WS_NEEDED      (WS_OFF_ROWS + (size_t)TOTPTS * CHANS * 4)  // ~90.6 MB

// ============================== fast path ==============================

// Zero the count region of d_out.
__global__ void k_zero_cnt(unsigned* __restrict__ cnt) {
    int i = blockIdx.x * blockDim.x + threadIdx.x;
    if (i < TOTVOX) cnt[i] = 0u;
}

// Per-point voxel id + histogram.
__global__ void k_vidx_hist(const float* __restrict__ coords,   // [B,3,NPTS]
                            const float* __restrict__ origin,   // [B,3]
                            int*         __restrict__ vidx,     // [TOTPTS]
                            unsigned*    __restrict__ cnt)      // [TOTVOX]
{
    int id = blockIdx.x * blockDim.x + threadIdx.x;
    if (id >= TOTPTS) return;
    int b = id / NPTS;
    int n = id - b * NPTS;

    const float* cb = coords + (size_t)b * 3 * NPTS;
    float x = cb[n];
    float y = cb[NPTS + n];
    float z = cb[2 * NPTS + n];
    float ox = origin[b * 3 + 0];
    float oy = origin[b * 3 + 1];
    float oz = origin[b * 3 + 2];

    // IEEE f32 division + floorf: must match numpy reference binning exactly.
    int ix = (int)floorf((x - ox) / VOXEL_SIZE);
    int iy = (int)floorf((y - oy) / VOXEL_SIZE);
    int iz = (int)floorf((z - oz) / VOXEL_SIZE);

    int v = -1;
    if ((unsigned)ix < GRID_W && (unsigned)iy < GRID_L && (unsigned)iz < GRID_H) {
        v = b * NVOX + ix * (GRID_L * GRID_H) + iy * GRID_H + iz;
        atomicAdd(&cnt[v], 1u);
    }
    vidx[id] = v;
}

// Scan level 1: per-block exclusive partials + block totals.
__global__ void k_scan1(const unsigned* __restrict__ cnt,
                        unsigned* __restrict__ offsets,
                        unsigned* __restrict__ sums)
{
    __shared__ unsigned s[SCAN_TPB];
    int t = threadIdx.x;
    int base = blockIdx.x * (SCAN_TPB * SCAN_EPT) + t * SCAN_EPT;

    uint4 a = ((const uint4*)(cnt + base))[0];
    uint4 c = ((const uint4*)(cnt + base))[1];
    unsigned e[SCAN_EPT] = {a.x, a.y, a.z, a.w, c.x, c.y, c.z, c.w};
    unsigned tot = 0;
    #pragma unroll
    for (int k = 0; k < SCAN_EPT; ++k) { unsigned v = e[k]; e[k] = tot; tot += v; }

    s[t] = tot;
    __syncthreads();
    // Hillis-Steele inclusive scan over thread totals
    #pragma unroll
    for (int off = 1; off < SCAN_TPB; off <<= 1) {
        unsigned v = (t >= off) ? s[t - off] : 0u;
        __syncthreads();
        s[t] += v;
        __syncthreads();
    }
    unsigned prefix = s[t] - tot;   // exclusive
    #pragma unroll
    for (int k = 0; k < SCAN_EPT; ++k) e[k] += prefix;

    uint4 o0 = {e[0], e[1], e[2], e[3]};
    uint4 o1 = {e[4], e[5], e[6], e[7]};
    ((uint4*)(offsets + base))[0] = o0;
    ((uint4*)(offsets + base))[1] = o1;

    if (t == SCAN_TPB - 1) sums[blockIdx.x] = s[t];
}

// Scan level 2: exclusive scan of the 864 block sums (single block).
__global__ void k_scan2(unsigned* __restrict__ sums) {
    __shared__ unsigned s[1024];
    int t = threadIdx.x;
    unsigned my = (t < SCAN_BLKS) ? sums[t] : 0u;
    s[t] = my;
    __syncthreads();
    #pragma unroll
    for (int off = 1; off < 1024; off <<= 1) {
        unsigned v = (t >= off) ? s[t - off] : 0u;
        __syncthreads();
        s[t] += v;
        __syncthreads();
    }
    if (t < SCAN_BLKS) sums[t] = s[t] - my;   // exclusive
}

// Scan level 3: add block prefixes.
__global__ void k_scan3(unsigned* __restrict__ offsets,
                        const unsigned* __restrict__ sums)
{
    int base = blockIdx.x * (SCAN_TPB * SCAN_EPT) + threadIdx.x * SCAN_EPT;
    unsigned p = sums[blockIdx.x];
    uint4 o0 = ((const uint4*)(offsets + base))[0];
    uint4 o1 = ((const uint4*)(offsets + base))[1];
    o0.x += p; o0.y += p; o0.z += p; o0.w += p;
    o1.x += p; o1.y += p; o1.z += p; o1.w += p;
    ((uint4*)(offsets + base))[0] = o0;
    ((uint4*)(offsets + base))[1] = o1;
}

// Scatter each in-bounds point's 16-channel attr row into its voxel segment.
// offsets[] is mutated into end-cursors (start recovered later as end - cnt).
__global__ void k_scatter_rows(const float* __restrict__ attrs,   // [B,C,NPTS]
                               const int*   __restrict__ vidx,    // [TOTPTS]
                               unsigned*    __restrict__ offsets, // [TOTVOX]
                               float*       __restrict__ rows)    // [TOTPTS,16]
{
    int id = blockIdx.x * blockDim.x + threadIdx.x;
    if (id >= TOTPTS) return;
    int v = vidx[id];
    if (v < 0) return;
    unsigned pos = atomicAdd(&offsets[v], 1u);

    int b = id / NPTS;
    int n = id - b * NPTS;
    const float* ab = attrs + (size_t)b * CHANS * NPTS + n;
    float4 r0, r1, r2, r3;
    r0.x = ab[0 * (size_t)NPTS];  r0.y = ab[1 * (size_t)NPTS];
    r0.z = ab[2 * (size_t)NPTS];  r0.w = ab[3 * (size_t)NPTS];
    r1.x = ab[4 * (size_t)NPTS];  r1.y = ab[5 * (size_t)NPTS];
    r1.z = ab[6 * (size_t)NPTS];  r1.w = ab[7 * (size_t)NPTS];
    r2.x = ab[8 * (size_t)NPTS];  r2.y = ab[9 * (size_t)NPTS];
    r2.z = ab[10 * (size_t)NPTS]; r2.w = ab[11 * (size_t)NPTS];
    r3.x = ab[12 * (size_t)NPTS]; r3.y = ab[13 * (size_t)NPTS];
    r3.z = ab[14 * (size_t)NPTS]; r3.w = ab[15 * (size_t)NPTS];

    float4* dst = (float4*)(rows + (size_t)pos * CHANS);
    dst[0] = r0; dst[1] = r1; dst[2] = r2; dst[3] = r3;
}

// Gather + finalize: one thread per voxel.
__global__ void k_gather_finalize(const float* __restrict__ rows,    // [TOTPTS,16]
                                  const unsigned* __restrict__ offsets, // end cursors
                                  unsigned* __restrict__ cnt_u,      // [TOTVOX] -> occ out
                                  float*    __restrict__ data)       // [B,C,NVOX]
{
    int i = blockIdx.x * blockDim.x + threadIdx.x;
    if (i >= TOTVOX) return;
    int b = i / NVOX;
    int v = i - b * NVOX;

    unsigned cnt = cnt_u[i];
    bool occ = (cnt >= MIN_PTS);

    float4 m0, m1, m2, m3;
    m0 = m1 = m2 = m3 = float4{0.f, 0.f, 0.f, 0.f};
    if (occ) {
        const float ninf = -__builtin_inff();
        m0 = m1 = m2 = m3 = float4{ninf, ninf, ninf, ninf};
        unsigned start = offsets[i] - cnt;
        for (unsigned j = 0; j < cnt; ++j) {
            const float4* row = (const float4*)(rows + (size_t)(start + j) * CHANS);
            float4 r0 = row[0], r1 = row[1], r2 = row[2], r3 = row[3];
            m0.x = fmaxf(m0.x, r0.x); m0.y = fmaxf(m0.y, r0.y);
            m0.z = fmaxf(m0.z, r0.z); m0.w = fmaxf(m0.w, r0.w);
            m1.x = fmaxf(m1.x, r1.x); m1.y = fmaxf(m1.y, r1.y);
            m1.z = fmaxf(m1.z, r1.z); m1.w = fmaxf(m1.w, r1.w);
            m2.x = fmaxf(m2.x, r2.x); m2.y = fmaxf(m2.y, r2.y);
            m2.z = fmaxf(m2.z, r2.z); m2.w = fmaxf(m2.w, r2.w);
            m3.x = fmaxf(m3.x, r3.x); m3.y = fmaxf(m3.y, r3.y);
            m3.z = fmaxf(m3.z, r3.z); m3.w = fmaxf(m3.w, r3.w);
        }
        // guard (attrs are finite in practice; matches reference semantics)
        float mv[16] = {m0.x,m0.y,m0.z,m0.w, m1.x,m1.y,m1.z,m1.w,
                        m2.x,m2.y,m2.z,m2.w, m3.x,m3.y,m3.z,m3.w};
        #pragma unroll
        for (int c = 0; c < CHANS; ++c) if (!isfinite(mv[c])) mv[c] = 0.f;
        m0 = float4{mv[0],mv[1],mv[2],mv[3]};   m1 = float4{mv[4],mv[5],mv[6],mv[7]};
        m2 = float4{mv[8],mv[9],mv[10],mv[11]}; m3 = float4{mv[12],mv[13],mv[14],mv[15]};
    }

    float* db = data + (size_t)b * CHANS * NVOX + v;
    db[0 * (size_t)NVOX] = m0.x;  db[1 * (size_t)NVOX] = m0.y;
    db[2 * (size_t)NVOX] = m0.z;  db[3 * (size_t)NVOX] = m0.w;
    db[4 * (size_t)NVOX] = m1.x;  db[5 * (size_t)NVOX] = m1.y;
    db[6 * (size_t)NVOX] = m1.z;  db[7 * (size_t)NVOX] = m1.w;
    db[8 * (size_t)NVOX] = m2.x;  db[9 * (size_t)NVOX] = m2.y;
    db[10 * (size_t)NVOX] = m2.z; db[11 * (size_t)NVOX] = m2.w;
    db[12 * (size_t)NVOX] = m3.x; db[13 * (size_t)NVOX] = m3.y;
    db[14 * (size_t)NVOX] = m3.z; db[15 * (size_t)NVOX] = m3.w;

    ((float*)cnt_u)[i] = occ ? 1.0f : 0.0f;
}

// ============================== fallback path (round-1) ==============================

__device__ __forceinline__ unsigned flip_f32(float f) {
    unsigned u = __float_as_uint(f);
    unsigned mask = (unsigned)(-(int)(u >> 31)) | 0x80000000u;
    return u ^ mask;
}
__device__ __forceinline__ float unflip_f32(unsigned u) {
    unsigned mask = ((u >> 31) - 1u) | 0x80000000u;
    return __uint_as_float(u ^ mask);
}
#define FLIP_NEG_INF 0x007FFFFFu

__global__ void pv_init(uint4* __restrict__ out) {
    const int DATA4 = BATCH * CHANS * NVOX / 4;
    const int TOT4  = BATCH * (CHANS + 1) * NVOX / 4;
    int i = blockIdx.x * blockDim.x + threadIdx.x;
    if (i < TOT4) {
        unsigned val = (i < DATA4) ? FLIP_NEG_INF : 0u;
        uint4 v; v.x = val; v.y = val; v.z = val; v.w = val;
        out[i] = v;
    }
}

__global__ void pv_scatter(const float* __restrict__ coords,
                           const float* __restrict__ attrs,
                           const float* __restrict__ origin,
                           unsigned*    __restrict__ data_u,
                           unsigned*    __restrict__ cnt)
{
    int id = blockIdx.x * blockDim.x + threadIdx.x;
    if (id >= TOTPTS) return;
    int b = id / NPTS;
    int n = id - b * NPTS;
    const float* cb = coords + (size_t)b * 3 * NPTS;
    float x = cb[n], y = cb[NPTS + n], z = cb[2 * NPTS + n];
    float ox = origin[b * 3 + 0], oy = origin[b * 3 + 1], oz = origin[b * 3 + 2];
    int ix = (int)floorf((x - ox) / VOXEL_SIZE);
    int iy = (int)floorf((y - oy) / VOXEL_SIZE);
    int iz = (int)floorf((z - oz) / VOXEL_SIZE);
    if ((unsigned)ix < GRID_W && (unsigned)iy < GRID_L && (unsigned)iz < GRID_H) {
        int flat = ix * (GRID_L * GRID_H) + iy * GRID_H + iz;
        atomicAdd(&cnt[b * NVOX + flat], 1u);
        const float* ab = attrs + (size_t)b * CHANS * NPTS + n;
        unsigned*    db = data_u + (size_t)b * CHANS * NVOX + flat;
        #pragma unroll
        for (int c = 0; c < CHANS; ++c)
            atomicMax(&db[(size_t)c * NVOX], flip_f32(ab[(size_t)c * NPTS]));
    }
}

__global__ void pv_finalize(unsigned* __restrict__ data_u,
                            unsigned* __restrict__ cnt_u)
{
    int id = blockIdx.x * blockDim.x + threadIdx.x;
    if (id >= TOTVOX) return;
    int b = id / NVOX;
    int v = id - b * NVOX;
    unsigned cnt = cnt_u[id];
    bool occ = (cnt >= MIN_PTS);
    ((float*)cnt_u)[id] = occ ? 1.0f : 0.0f;
    unsigned* db = data_u + (size_t)b * CHANS * NVOX + v;
    #pragma unroll
    for (int c = 0; c < CHANS; ++c) {
        float f = unflip_f32(db[(size_t)c * NVOX]);
        ((float*)db)[(size_t)c * NVOX] = (occ && isfinite(f)) ? f : 0.0f;
    }
}

// ============================== launch ==============================

extern "C" void kernel_launch(void* const* d_in, const int* in_sizes, int n_in,
                              void* d_out, int out_size, void* d_ws, size_t ws_size,
                              hipStream_t stream) {
    const float* coords = (const float*)d_in[0];  // [4,3,480,640]
    const float* attrs  = (const float*)d_in[1];  // [4,16,480,640]
    const float* origin = (const float*)d_in[2];  // [4,3]

    float* out = (float*)d_out;
    float* data = out;                                        // [B,C,NVOX]
    unsigned* cnt = (unsigned*)(out + (size_t)BATCH * CHANS * NVOX); // [B,NVOX]

    if (ws_size >= WS_NEEDED) {
        char* ws = (char*)d_ws;
        unsigned* offsets = (unsigned*)(ws + WS_OFF_OFFSETS);
        int*      vidx    = (int*)(ws + WS_OFF_VIDX);
        unsigned* sums    = (unsigned*)(ws + WS_OFF_SUMS);
        float*    rows    = (float*)(ws + WS_OFF_ROWS);

        k_zero_cnt<<<(TOTVOX + 255) / 256, 256, 0, stream>>>(cnt);
        k_vidx_hist<<<(TOTPTS + 255) / 256, 256, 0, stream>>>(coords, origin, vidx, cnt);
        k_scan1<<<SCAN_BLKS, SCAN_TPB, 0, stream>>>(cnt, offsets, sums);
        k_scan2<<<1, 1024, 0, stream>>>(sums);
        k_scan3<<<SCAN_BLKS, SCAN_TPB, 0, stream>>>(offsets, sums);
        k_scatter_rows<<<(TOTPTS + 255) / 256, 256, 0, stream>>>(attrs, vidx, offsets, rows);
        k_gather_finalize<<<(TOTVOX + 255) / 256, 256, 0, stream>>>(rows, offsets, cnt, data);
    } else {
        const int TOT4 = BATCH * (CHANS + 1) * NVOX / 4;
        pv_init<<<(TOT4 + 255) / 256, 256, 0, stream>>>((uint4*)d_out);
        pv_scatter<<<(TOTPTS + 255) / 256, 256, 0, stream>>>(coords, attrs, origin,
                                                             (unsigned*)data, cnt);
        pv_finalize<<<(TOTVOX + 255) / 256, 256, 0, stream>>>((unsigned*)data, cnt);
    }
}